// Round 1
// baseline (147.272 us; speedup 1.0000x reference)
//
#include <hip/hip_runtime.h>

// Problem constants (static in the reference: D1=D2=32, ADD1=ADD2=16, BATCH=8)
constexpr int FOCK_DIM = 4656;        // m*(m+1)/2 with m=96, 2 photons
constexpr int N        = 1024;        // D1*D2
constexpr int ROW_VEC  = FOCK_DIM / 4; // 1164 float4 per output row

// --- build inverse map: inv[f] = image index i if fock_idx[i]==f else -1 ---
__global__ void init_inv_kernel(int* __restrict__ inv) {
    int i = blockIdx.x * blockDim.x + threadIdx.x;
    if (i < FOCK_DIM) inv[i] = -1;
}

__global__ void fill_inv_kernel(const int* __restrict__ fock_idx, int* __restrict__ inv) {
    int i = blockIdx.x * blockDim.x + threadIdx.x;
    if (i < N) inv[fock_idx[i]] = i;
}

// --- main gather kernel: one block per output row (b, r) ---
// out[b, r, c] = (inv[r]>=0 && inv[c]>=0) ? in[b, inv[r], inv[c]] : 0
__global__ __launch_bounds__(256) void scatter_rows_kernel(
    const float* __restrict__ in,
    const int*   __restrict__ inv,
    float*       __restrict__ out) {

    const int br = blockIdx.x;          // b * FOCK_DIM + r
    const int b  = br / FOCK_DIM;
    const int r  = br - b * FOCK_DIM;
    const int invr = inv[r];

    float4* __restrict__ orow = reinterpret_cast<float4*>(out + (size_t)br * FOCK_DIM);

    if (invr < 0) {
        // dead row: pure zero stream
        const float4 z = make_float4(0.f, 0.f, 0.f, 0.f);
        for (int c4 = threadIdx.x; c4 < ROW_VEC; c4 += 256) {
            orow[c4] = z;
        }
        return;
    }

    // live row: stage the 4 KB input row in LDS, gather by inv[c]
    __shared__ float row[N];
    const float* __restrict__ irow = in + ((size_t)b * N + (size_t)invr) * N;
    for (int i = threadIdx.x; i < N; i += 256) row[i] = irow[i];
    __syncthreads();

    const int4* __restrict__ inv4 = reinterpret_cast<const int4*>(inv);
    for (int c4 = threadIdx.x; c4 < ROW_VEC; c4 += 256) {
        const int4 iv = inv4[c4];
        float4 v;
        v.x = (iv.x >= 0) ? row[iv.x] : 0.f;
        v.y = (iv.y >= 0) ? row[iv.y] : 0.f;
        v.z = (iv.z >= 0) ? row[iv.z] : 0.f;
        v.w = (iv.w >= 0) ? row[iv.w] : 0.f;
        orow[c4] = v;
    }
}

extern "C" void kernel_launch(void* const* d_in, const int* in_sizes, int n_in,
                              void* d_out, int out_size, void* d_ws, size_t ws_size,
                              hipStream_t stream) {
    const float* in       = (const float*)d_in[0];   // [B, 1024, 1024] fp32
    const int*   fock_idx = (const int*)d_in[1];     // [1024] int
    float*       out      = (float*)d_out;           // [B, 4656, 4656] fp32
    int*         inv      = (int*)d_ws;              // 4656 int32 scratch

    const int B = in_sizes[0] / (N * N);             // 8

    init_inv_kernel<<<(FOCK_DIM + 255) / 256, 256, 0, stream>>>(inv);
    fill_inv_kernel<<<(N + 255) / 256, 256, 0, stream>>>(fock_idx, inv);
    scatter_rows_kernel<<<B * FOCK_DIM, 256, 0, stream>>>(in, inv, out);
}